// Round 5
// baseline (156.863 us; speedup 1.0000x reference)
//
#include <hip/hip_runtime.h>
#include <hip/hip_bf16.h>

// y_i = x_i^T Q x_i + b^T x_i + c ; N=16384, D=1024, fp32.
// Round 5: same A-resident R=64/KH=256 design as round 4, but 256-thread
// blocks (4 waves) x 512 grid -> TWO independent blocks per CU. Round 4's
// grid=256 put all 8 waves of a CU behind ONE barrier: every xv/Q load
// straggler stalled the whole CU (MfmaUtil 17%, 4.7k cyc/tile vs 1.2k MFMA).
// Co-resident independent blocks interleave their barrier drains.
// Register budget (the round-3 lesson): __launch_bounds__(256,2) -> 256
// unified regs/wave; 128 AGPR (A-frags, asm "+a" pinned) + ~120 VGPR fits.
// xv stays single-buffered to stay under budget.

#define DD 1024
#define KH 256           // K per block (K-split 4)
#define KSTEP 8          // KH/32 MFMA k-steps per tile
#define NTT 32           // column tiles per col-half (512 n / 16)
#define LDS_ROW 264      // shorts: 256 + 8 pad (528 B, 16B-aligned rows)

typedef short v8s __attribute__((ext_vector_type(8)));
typedef float v4f __attribute__((ext_vector_type(4)));

__device__ __forceinline__ short f2b(float f) {
    union { __hip_bfloat16 h; short s; } u;
    u.h = __float2bfloat16(f);
    return u.s;
}

__global__ __launch_bounds__(256, 2)
void quad_kernel(const float* __restrict__ x, const float* __restrict__ Q,
                 const float* __restrict__ bvec, const float* __restrict__ cptr,
                 float* __restrict__ y)
{
    __shared__ short lq[2][16 * LDS_ROW];   // 2 x 8.25 KB staging buffers

    const int tid  = threadIdx.x;
    const int lane = tid & 63;
    const int wave = tid >> 6;
    const int quad = lane >> 4;
    const int l15  = lane & 15;

    const int seg  = blockIdx.x & 7;     // kq*2 + cs
    const int rblk = blockIdx.x >> 3;    // 0..63
    const int kq   = seg >> 1;           // K quarter 0..3
    const int cs   = seg & 1;            // column half 0..1

    const int row_base = rblk * 256 + wave * 64;   // 64 rows per wave
    const int kofs  = kq * KH;
    const int tbase = cs * NTT;

    // ---- Staging map: tile = 16 Qrows x 256 floats = 1024 float4 / 256 thr
    int s_nn[4], s_k4[4];
    #pragma unroll
    for (int i = 0; i < 4; ++i) {
        const int idx = tid + i * 256;
        s_nn[i] = idx >> 6;        // 0..15
        s_k4[i] = idx & 63;        // float4 within KH
    }

    // prefetch tile 0 (issued before the A-load so it overlaps the prologue)
    float4 pf[4];
    #pragma unroll
    for (int i = 0; i < 4; ++i)
        pf[i] = *(const float4*)(Q + (size_t)(tbase * 16 + s_nn[i]) * DD + kofs + s_k4[i] * 4);

    // ---- Phase 1: A = x[64 rows][kofs..kofs+256) bf16 frags in AGPRs ----
    // A layout (16x16x32): m = lane&15, k = quad*8 + j (8 contiguous bf16)
    v8s a[4][KSTEP];
    #pragma unroll
    for (int g = 0; g < 4; ++g) {
        const float* xr = x + (size_t)(row_base + g * 16 + l15) * DD + kofs + quad * 8;
        #pragma unroll
        for (int s = 0; s < KSTEP; ++s) {
            const float4 f0 = *(const float4*)(xr + s * 32);
            const float4 f1 = *(const float4*)(xr + s * 32 + 4);
            v8s t;
            t[0]=f2b(f0.x); t[1]=f2b(f0.y); t[2]=f2b(f0.z); t[3]=f2b(f0.w);
            t[4]=f2b(f1.x); t[5]=f2b(f1.y); t[6]=f2b(f1.z); t[7]=f2b(f1.w);
            a[g][s] = t;
            asm volatile("" : "+a"(a[g][s]));   // force AGPR residency
        }
    }

    float acc[4][4];
    #pragma unroll
    for (int g = 0; g < 4; ++g)
        #pragma unroll
        for (int r = 0; r < 4; ++r) acc[g][r] = 0.f;

    for (int t = 0; t < NTT; ++t) {
        const int tg = tbase + t;

        // store staged tile (fp32 -> bf16) into buf t&1
        short* dst = &lq[t & 1][0];
        #pragma unroll
        for (int i = 0; i < 4; ++i) {
            const float4 f = pf[i];
            short4 s;
            s.x=f2b(f.x); s.y=f2b(f.y); s.z=f2b(f.z); s.w=f2b(f.w);
            *(short4*)&dst[s_nn[i] * LDS_ROW + s_k4[i] * 4] = s;
        }
        __syncthreads();

        // next tile's prefetch AFTER the barrier: in flight across MFMA
        if (t + 1 < NTT) {
            #pragma unroll
            for (int i = 0; i < 4; ++i)
                pf[i] = *(const float4*)(Q + (size_t)((tg + 1) * 16 + s_nn[i]) * DD + kofs + s_k4[i] * 4);
        }

        // fused-dot operands for this tile (consumed after the MFMAs)
        const int n = tg * 16 + l15;
        const float bn = (kq == 0) ? bvec[n] : 0.f;
        float xv[4][4];
        {
            const float* xc = x + (size_t)(row_base + quad * 4) * DD + n;
            #pragma unroll
            for (int g = 0; g < 4; ++g)
                #pragma unroll
                for (int r = 0; r < 4; ++r)
                    xv[g][r] = xc[(size_t)(g * 16 + r) * DD];
        }

        // MFMA: each B-frag feeds all 4 A-groups (4 independent chains)
        v4f cf[4];
        #pragma unroll
        for (int g = 0; g < 4; ++g) cf[g] = (v4f){0.f, 0.f, 0.f, 0.f};
        const short* bp = &lq[t & 1][l15 * LDS_ROW + quad * 8];
        #pragma unroll
        for (int s = 0; s < KSTEP; ++s) {
            const v8s bfrag = *(const v8s*)(bp + s * 32);
            #pragma unroll
            for (int g = 0; g < 4; ++g)
                cf[g] = __builtin_amdgcn_mfma_f32_16x16x32_bf16(a[g][s], bfrag, cf[g], 0, 0, 0);
        }

        // fused dot: C layout col = lane&15, row = quad*4 + reg
        #pragma unroll
        for (int g = 0; g < 4; ++g)
            #pragma unroll
            for (int r = 0; r < 4; ++r)
                acc[g][r] += (cf[g][r] + bn) * xv[g][r];
    }

    // ---- reduce across the 16 lanes of each quad, atomic into y ----
    const float cc = (seg == 0) ? cptr[0] : 0.f;  // c added once per row
    #pragma unroll
    for (int g = 0; g < 4; ++g) {
        #pragma unroll
        for (int r = 0; r < 4; ++r) {
            float v = acc[g][r];
            v += __shfl_xor(v, 1); v += __shfl_xor(v, 2);
            v += __shfl_xor(v, 4); v += __shfl_xor(v, 8);
            if (l15 == 0)
                atomicAdd(&y[row_base + g * 16 + quad * 4 + r], v + cc);
        }
    }
}

extern "C" void kernel_launch(void* const* d_in, const int* in_sizes, int n_in,
                              void* d_out, int out_size, void* d_ws, size_t ws_size,
                              hipStream_t stream)
{
    const float* x = (const float*)d_in[0];
    const float* Q = (const float*)d_in[1];
    const float* b = (const float*)d_in[2];
    const float* c = (const float*)d_in[3];
    float* y = (float*)d_out;

    hipMemsetAsync(y, 0, (size_t)out_size * sizeof(float), stream);
    quad_kernel<<<dim3(512), dim3(256), 0, stream>>>(x, Q, b, c, y);
}